// Round 1
// baseline (9.674 us; speedup 1.0000x reference)
//
#include <hip/hip_runtime.h>

// LearnAdjacency collapses algebraically:
//   - LayerNorm over a trailing axis of SIZE 1: mu == x, var == 0
//     => y = 0/sqrt(eps)*gamma + beta = beta (constant, independent of X, w, b, gamma)
//   - row softmax of a constant row of length N=256 with eps-denominator:
//     => exp(0) / (256 + 1e-8) = 1/(256+1e-8) for every entry (independent of beta)
// So adj[b,i,j] == 1/(256+1e-8) for ALL inputs. In f32, 256.0f + 1e-8f == 256.0f,
// so the value is exactly 2^-8 = 0.00390625.
// Kernel is therefore a vectorized constant fill of d_out (8*256*256 = 524288 floats).

__global__ __launch_bounds__(256) void LearnAdjacency_fill_kernel(float4* __restrict__ out,
                                                                  int n4, float val) {
    int i = blockIdx.x * blockDim.x + threadIdx.x;
    if (i < n4) {
        out[i] = make_float4(val, val, val, val);
    }
}

extern "C" void kernel_launch(void* const* d_in, const int* in_sizes, int n_in,
                              void* d_out, int out_size, void* d_ws, size_t ws_size,
                              hipStream_t stream) {
    (void)d_in; (void)in_sizes; (void)n_in; (void)d_ws; (void)ws_size;

    const int N = 256;                     // row length of the softmax
    const float denom = (float)N + 1e-8f;  // == 256.0f in f32
    const float val = 1.0f / denom;        // == 0.00390625 exactly

    // out_size = 8*256*256 = 524288, divisible by 4.
    int n4 = out_size / 4;
    int block = 256;
    int grid = (n4 + block - 1) / block;

    LearnAdjacency_fill_kernel<<<grid, block, 0, stream>>>(
        reinterpret_cast<float4*>(d_out), n4, val);
}